// Round 2
// baseline (880.723 us; speedup 1.0000x reference)
//
#include <hip/hip_runtime.h>

// CountPrediction: per-cell closed-form (tilde_u, tilde_s).
// CELLS=1e6, GENES=200. Only column g of t is used -> strided gather at
// 800 B stride: HBM-line-granularity bound (~64-128 MB fetch for 4 MB useful).
// Roofline estimate ~13-24 us at 6.3 TB/s achievable.

#define CELLS_N 1000000
#define GENES_N 200

__global__ __launch_bounds__(256) void count_prediction_kernel(
    const float* __restrict__ out3,   // (CELLS, 3): alpha, gamma, beta
    const float* __restrict__ k,
    const float* __restrict__ d,
    const float* __restrict__ t0_g3,
    const float* __restrict__ u0_g3,
    const float* __restrict__ t,      // (CELLS, GENES)
    const int*  __restrict__ gene_index,
    float* __restrict__ outp,         // [0..CELLS): tilde_u, [CELLS..2*CELLS): tilde_s
    int cells, int genes)
{
    const int i = blockIdx.x * blockDim.x + threadIdx.x;
    if (i >= cells) return;

    // Uniform scalars (wave-uniform -> scalar loads, L2-hot)
    const int   g   = gene_index[0];
    const float kg  = k[g];
    const float dg  = d[g];
    const float t0g = t0_g3[g];
    const float u0g = u0_g3[g];

    // --- issue the long-latency strided gather first ---
    const float tg = t[(long long)i * genes + g];   // own cache line per lane

    // (CELLS,3) row: 3 consecutive floats per thread; contiguous across the wave
    const float alpha  = out3[3 * i + 0];
    const float gamma0 = out3[3 * i + 1];
    const float beta0  = out3[3 * i + 2];

    // Exact reference semantics & order (branchless):
    //   beta  = where(beta == 0,      beta + 0.75, beta)
    //   beta  = where(beta == gamma0, beta + 0.75, beta)   (compares vs ORIGINAL gamma)
    //   gamma = where(gamma == 0,     gamma + 0.75, gamma)
    float beta  = (beta0 == 0.0f)   ? beta0 + 0.75f : beta0;
    beta        = (beta  == gamma0) ? beta  + 0.75f : beta;
    const float gamma = (gamma0 == 0.0f) ? gamma0 + 0.75f : gamma0;

    // sigmoid(kg * (tg - t0g - dg))
    const float x  = kg * (tg - t0g - dg);
    const float S  = 1.0f / (1.0f + expf(-x));
    const float nS = 1.0f - S;

    const float tgs = tg - t0g;
    const float eb  = expf(-beta  * tg);
    const float eg  = expf(-gamma * tg);
    const float eb0 = expf(-beta  * tgs);
    const float eg0 = expf(-gamma * tgs);

    const float ab = alpha / beta;
    const float ag = alpha / gamma;

    const float inv_gb = 1.0f / (gamma - beta);
    const float a_gb   = alpha * inv_gb;
    const float bu0_gb = beta * u0g * inv_gb;

    const float tilde_u = ab * (1.0f - eb) * nS + ab * S + (u0g * eb0 - ab) * S;
    const float tilde_s = (ag * (1.0f - eg) + a_gb * (eg - eb)) * nS
                        + ag * S
                        + bu0_gb * (eg0 - eb0) * S;

    outp[i]         = tilde_u;
    outp[cells + i] = tilde_s;
}

extern "C" void kernel_launch(void* const* d_in, const int* in_sizes, int n_in,
                              void* d_out, int out_size, void* d_ws, size_t ws_size,
                              hipStream_t stream)
{
    const float* out3  = (const float*)d_in[0];
    const float* k     = (const float*)d_in[1];
    const float* d     = (const float*)d_in[2];
    const float* t0_g3 = (const float*)d_in[3];
    const float* u0_g3 = (const float*)d_in[4];
    const float* t     = (const float*)d_in[5];
    const int*   gidx  = (const int*)d_in[6];
    float* outp        = (float*)d_out;

    const int cells = CELLS_N;
    const int genes = GENES_N;

    const int block = 256;
    const int grid  = (cells + block - 1) / block;  // 3907 blocks

    count_prediction_kernel<<<grid, block, 0, stream>>>(
        out3, k, d, t0_g3, u0_g3, t, gidx, outp, cells, genes);
}